// Round 7
// baseline (655.191 us; speedup 1.0000x reference)
//
#include <hip/hip_runtime.h>
#include <stdint.h>

// VQ-VAE codebook quantize: z (8,256,16,32,32) f32, codebook (1024,256) f32.
// Outputs (concat in d_out, f32): quantized, st (== quantized fwd), indices.
// R11:
//  - rescore fused into the sweep tail: cand/cnt/best kept in LDS, z-tile
//    staged into the freed B double-buffer (R10-proven chunked rescore body,
//    identity heavy map, cnS for ||e||^2). All ids finalized in the sweep;
//    candW/cntW/abW global round-trips deleted.
//  - output writes rebuilt as d-plane streamer vq_out_k: cbT (transposed
//    codebook, 1MB, emitted coalesced by cconv) rows + ids staged in LDS,
//    q/st written as 8KB-contiguous d-plane runs (fill-kernel pattern) --
//    replaces the 256B-segment region gather that capped R10 at 2 TB/s.

constexpr int Dd  = 256;
constexpr int SPB = 16384;          // 16*32*32
constexpr int Nn  = 131072;         // 8*SPB tokens
constexpr int Kk  = 1024;
constexpr int CCAP = 16;            // candidate cap per token (avg ~1.2, P(>16)~0)
#define WWIN 2.2e-3f                // collect window; >= 2x approx err + quant

typedef short short8 __attribute__((ext_vector_type(8)));
typedef float v4f    __attribute__((ext_vector_type(4)));

__device__ __forceinline__ unsigned bf16pk(float a, float b){  // RNE pack 2xbf16
  unsigned ua = __float_as_uint(a), ub = __float_as_uint(b);
  ua = (ua + 0x7fffu + ((ua >> 16) & 1u)) >> 16;
  ub = (ub + 0x7fffu + ((ub >> 16) & 1u)) & 0xffff0000u;
  return ua | ub;
}
__device__ __forceinline__ short8 frg(uint4 u){
  union { uint4 a; short8 b; } x; x.a = u; return x.b;
}
__device__ __forceinline__ v4f mfma16(short8 a, short8 b, v4f c){
  return __builtin_amdgcn_mfma_f32_16x16x32_bf16(a, b, c, 0, 0, 0);
}
__device__ __forceinline__ void dma16(const void* g, void* l){
  __builtin_amdgcn_global_load_lds((const __attribute__((address_space(1))) void*)g,
                                   (__attribute__((address_space(3))) void*)l, 16, 0, 0);
}

// ---------- prepass: ||e_k||^2 ----------
__global__ __launch_bounds__(64) void cnorm_k(const float* __restrict__ cb,
                                              float* __restrict__ cn){
  const int k = blockIdx.x, l = threadIdx.x;
  const float* row = cb + (size_t)k * Dd;
  float s = 0.f;
  #pragma unroll
  for (int c = 0; c < Dd; c += 64){ float v = row[c + l]; s += v * v; }
  #pragma unroll
  for (int off = 32; off > 0; off >>= 1) s += __shfl_down(s, off, 64);
  if (l == 0) cn[k] = s;
}

// ---------- prepass: codebook -> bf16 fragment plane + transposed cbT -------
__global__ __launch_bounds__(256) void cconv_k(const float* __restrict__ cb,
                                               uint4* __restrict__ Bg,
                                               float* __restrict__ cbT){
  const int cc = blockIdx.x, n = threadIdx.x;
  const float* row = cb + (size_t)(cc * 256 + n) * Dd;
  for (int dc = 0; dc < 8; dc++){
    float v[32];
    const float4* rp = (const float4*)(row + dc * 32);
    #pragma unroll
    for (int q = 0; q < 8; q++){
      float4 f = rp[q]; v[4*q]=f.x; v[4*q+1]=f.y; v[4*q+2]=f.z; v[4*q+3]=f.w;
    }
    #pragma unroll
    for (int j = 0; j < 32; j++)
      cbT[(size_t)(dc*32 + j) * 1024 + cc*256 + n] = v[j];
    unsigned hv[16];
    #pragma unroll
    for (int p = 0; p < 16; p++) hv[p] = bf16pk(v[2*p], v[2*p+1]);
    size_t base = ((size_t)cc * 8 + dc) * 1024;
    #pragma unroll
    for (int kq = 0; kq < 4; kq++)
      Bg[base + (size_t)kq*256 + n] = make_uint4(hv[4*kq],hv[4*kq+1],hv[4*kq+2],hv[4*kq+3]);
  }
}

// ---------- sweep epilogue: pack, wave-local argmin, window collect (LDS) ----
__device__ __forceinline__ void epi(const v4f (&acc)[4], const int c,
                                    const int li, const int lq, const int w,
                                    const float* cnS,
                                    unsigned (&bestR)[4], unsigned (&thrU)[4],
                                    int (&cntR)[4],
                                    unsigned short* __restrict__ candL){
  float cnv[4];
  #pragma unroll
  for (int ni = 0; ni < 4; ni++) cnv[ni] = cnS[c*64 + ni*16 + li];
  const int codeB = c*64 + li;
  #pragma unroll
  for (int r = 0; r < 4; r++){
    unsigned pv[4];
    unsigned pm = 0xFFFFFFFFu;
    #pragma unroll
    for (int ni = 0; ni < 4; ni++){
      float s = fmaf(acc[ni][r], -2.0f, cnv[ni]);            // zn cancels
      unsigned u = __float_as_uint(s);
      u ^= (unsigned)((int)u >> 31) | 0x80000000u;            // sortable uint
      unsigned p = (u & 0xFFFFFC00u) | (unsigned)(codeB + ni*16);
      pv[ni] = p;
      pm = (pm < p) ? pm : p;
    }
    unsigned pmw = pm;
    #pragma unroll
    for (int off = 1; off < 16; off <<= 1){
      unsigned o = (unsigned)__shfl_xor((int)pmw, off, 16);
      pmw = (pmw < o) ? pmw : o;
    }
    if (pmw <= bestR[r]){                   // always true at c==0
      bestR[r] = pmw;
      unsigned bp = pmw & 0xFFFFFC00u;
      unsigned fb = (bp & 0x80000000u) ? (bp ^ 0x80000000u) : ~bp;
      float thrf = __uint_as_float(fb) + WWIN;
      unsigned tu = __float_as_uint(thrf);
      tu ^= (unsigned)((int)tu >> 31) | 0x80000000u;
      thrU[r] = tu | 1023u;                 // inclusive of code bits
    }
    if (__any(pm <= thrU[r])){              // fast-skip most chunks
      const int row = w*16 + lq*4 + r;
      int base = cntR[r];
      #pragma unroll
      for (int ni = 0; ni < 4; ni++){
        const unsigned p = pv[ni];
        const bool pass = (p <= thrU[r]);
        unsigned long long bal = __ballot(pass);
        const unsigned bq = (unsigned)(bal >> (lq*16)) & 0xFFFFu;
        if (pass){
          int pos = base + __popc(bq & ((1u << li) - 1u));
          if (pos < CCAP)
            candL[row*CCAP + pos] = (unsigned short)(p & 1023u);
        }
        base += __popc(bq);
      }
      cntR[r] = base;
    }
  }
}

// ---------- phase 1: MFMA sweep + fused exact rescore ----------
__global__ __launch_bounds__(512, 4) void vq_sweep_k(const float* __restrict__ z,
                                                     const float* __restrict__ cb,
                                                     const uint4* __restrict__ Bg,
                                                     const float* __restrict__ cnG,
                                                     int* __restrict__ idsW,
                                                     float* __restrict__ out){
  __shared__ uint4 Bs[2][2048];    // 64 KiB: [buf][dc 0..7][kq 0..3][n 0..63]
  __shared__ float cnS[1024];      // 4 KiB
  __shared__ uint4 candU[128][2];  // 4 KiB
  __shared__ int cntS[128];
  __shared__ int abS[128];
  __shared__ int anyH;
  unsigned short* candL = (unsigned short*)candU;

  const int tid = threadIdx.x, bId = blockIdx.x;
  const int w = tid >> 6, ln = tid & 63;
  const int li = ln & 15, lq = ln >> 4;

  if (tid == 0) anyH = 0;

  // ---- stage cn (4 KiB) + B chunk 0 first ----
  if (w < 4) dma16((const uint4*)cnG + w*64 + ln, (uint4*)&cnS[w*256]);
  int bOff[4];
  #pragma unroll
  for (int j = 0; j < 4; j++){
    const int f = j*512 + tid;              // [dc][kq][nl] flat
    bOff[j] = (f >> 8)*1024 + ((f >> 6) & 3)*256 + (f & 63);
  }
  #pragma unroll
  for (int j = 0; j < 4; j++)
    dma16(Bg + bOff[j], &Bs[0][j*512 + w*64]);

  // ---- A: z -> bf16 frags in registers (verified bf16pk chain) ----
  const int tok0 = bId * 128;
  const int b = tok0 >> 14;                 // uniform per block
  const int s0 = tok0 & 16383;
  const float* zb = z + (size_t)b * Dd * SPB + s0;
  short8 aF[8];
  const int tl8 = w*16 + li;                // token within block (A-frag row)
  #pragma unroll
  for (int kk = 0; kk < 8; kk++){
    float v[8];
    #pragma unroll
    for (int j = 0; j < 8; j++)
      v[j] = zb[(size_t)(kk*32 + lq*8 + j) * SPB + tl8];
    union { unsigned u[4]; short8 s8; } x;
    #pragma unroll
    for (int p = 0; p < 4; p++) x.u[p] = bf16pk(v[2*p], v[2*p+1]);
    aF[kk] = x.s8;
  }

  unsigned bestR[4], thrU[4]; int cntR[4];
  #pragma unroll
  for (int i = 0; i < 4; i++){ bestR[i] = 0xFFFFFFFFu; thrU[i] = 0u; cntR[i] = 0; }

  v4f accA[4], accB[4];
  const v4f vz = {0.f, 0.f, 0.f, 0.f};

  for (int cp = 0; cp < 8; cp++){
    const int c0 = cp*2, c1 = c0 + 1;

    // ===== chunk c0 (buf 0) =====
    {
      const int cn1 = c0 + 1;
      const int srcB = (cn1 >> 2)*8192 + (cn1 & 3)*64;
      #pragma unroll
      for (int j = 0; j < 4; j++)
        dma16(Bg + srcB + bOff[j], &Bs[1][j*512 + w*64]);
      asm volatile("s_waitcnt vmcnt(4)" ::: "memory");
      __builtin_amdgcn_s_barrier();
      asm volatile("" ::: "memory");

      #pragma unroll
      for (int ni = 0; ni < 4; ni++) accA[ni] = vz;
      const uint4* Bbase = &Bs[0][lq*64 + li];
      __builtin_amdgcn_s_setprio(1);
      #pragma unroll
      for (int kk = 0; kk < 8; kk++){
        short8 b0 = frg(Bbase[kk*256 +  0]);
        short8 b1 = frg(Bbase[kk*256 + 16]);
        short8 b2 = frg(Bbase[kk*256 + 32]);
        short8 b3 = frg(Bbase[kk*256 + 48]);
        accA[0] = mfma16(aF[kk], b0, accA[0]);
        accA[1] = mfma16(aF[kk], b1, accA[1]);
        accA[2] = mfma16(aF[kk], b2, accA[2]);
        accA[3] = mfma16(aF[kk], b3, accA[3]);
      }
      __builtin_amdgcn_s_setprio(0);
      if (cp)
        epi(accB, c0 - 1, li, lq, w, cnS, bestR, thrU, cntR, candL);
      __builtin_amdgcn_s_barrier();
      asm volatile("" ::: "memory");
    }

    // ===== chunk c1 (buf 1) =====
    {
      if (c1 < 15){
        const int cn1 = c1 + 1;
        const int srcB = (cn1 >> 2)*8192 + (cn1 & 3)*64;
        #pragma unroll
        for (int j = 0; j < 4; j++)
          dma16(Bg + srcB + bOff[j], &Bs[0][j*512 + w*64]);
        asm volatile("s_waitcnt vmcnt(4)" ::: "memory");
      } else {
        asm volatile("s_waitcnt vmcnt(0)" ::: "memory");
      }
      __builtin_amdgcn_s_barrier();
      asm volatile("" ::: "memory");

      #pragma unroll
      for (int ni = 0; ni < 4; ni++) accB[ni] = vz;
      const uint4* Bbase = &Bs[1][lq*64 + li];
      __builtin_amdgcn_s_setprio(1);
      #pragma unroll
      for (int kk = 0; kk < 8; kk++){
        short8 b0 = frg(Bbase[kk*256 +  0]);
        short8 b1 = frg(Bbase[kk*256 + 16]);
        short8 b2 = frg(Bbase[kk*256 + 32]);
        short8 b3 = frg(Bbase[kk*256 + 48]);
        accB[0] = mfma16(aF[kk], b0, accB[0]);
        accB[1] = mfma16(aF[kk], b1, accB[1]);
        accB[2] = mfma16(aF[kk], b2, accB[2]);
        accB[3] = mfma16(aF[kk], b3, accB[3]);
      }
      __builtin_amdgcn_s_setprio(0);
      epi(accA, c0, li, lq, w, cnS, bestR, thrU, cntR, candL);
      __builtin_amdgcn_s_barrier();
      asm volatile("" ::: "memory");
    }
  }
  epi(accB, 15, li, lq, w, cnS, bestR, thrU, cntR, candL);

  // ---- dump per-token state to LDS; light tokens finalized now ----
  if (li == 0){
    #pragma unroll
    for (int r = 0; r < 4; r++){
      const int row = w*16 + lq*4 + r;
      const int tok = tok0 + row;
      cntS[row] = cntR[r];
      abS[row]  = (int)(bestR[r] & 1023u);
      if (cntR[r] == 1){
        const int code = (int)(bestR[r] & 1023u);
        idsW[tok] = code;
        out[(size_t)2 * Nn * Dd + tok] = (float)code;
      } else {
        anyH = 1;
      }
    }
  }
  __syncthreads();

  // ---- fused exact fp32 rescore (identity map; R10-proven body) ----
  if (anyH){
    float* zS = (float*)&Bs[0][0];                 // 32 KiB tile [64][128]
    const int tl = tid;                            // token-in-region (tid<128)
    const int cntL = (tid < 128) ? cntS[tid] : 0;
    const bool act = (cntL > 1);
    const int tok = tok0 + tl;
    int n = 0, abest = 0;
    bool ovf = false;
    unsigned short cds[CCAP];
    if (act){
      n = cntL;
      ovf = (n > CCAP);
      if (ovf) n = CCAP;
      *(uint4*)&cds[0] = candU[tl][0];
      *(uint4*)&cds[8] = candU[tl][1];
      abest = abS[tl];
    }
    const int eIdx = act ? (ovf ? abest : (int)cds[0]) : 0;

    float accs[CCAP];
    #pragma unroll
    for (int i = 0; i < CCAP; i++) accs[i] = 0.f;
    float accE = 0.f, za = 0.f;

    for (int ch = 0; ch < 4; ch++){
      if (ch) __syncthreads();
      #pragma unroll
      for (int rr = 0; rr < 4; rr++){           // 2048 float4 / 512 threads
        const int f4 = rr*512 + tid;
        const int row = f4 >> 5, c4 = f4 & 31;
        const float4 v = *(const float4*)(zb + (size_t)(ch*64 + row) * SPB + c4*4);
        *(float4*)&zS[row*128 + c4*4] = v;
      }
      __syncthreads();
      if (act){
        #pragma unroll 8
        for (int d = 0; d < 64; d++){
          const float v = zS[d*128 + tl];
          za = fmaf(v, v, za);
        }
        #pragma unroll
        for (int ci = 0; ci < CCAP; ci++){
          if (ci < n){
            const float* cr = cb + (size_t)cds[ci] * Dd + ch*64;
            float a = accs[ci];
            #pragma unroll
            for (int d = 0; d < 64; d += 4){
              const float4 cv = *(const float4*)(cr + d);
              a = fmaf(zS[(d+0)*128 + tl], cv.x, a);
              a = fmaf(zS[(d+1)*128 + tl], cv.y, a);
              a = fmaf(zS[(d+2)*128 + tl], cv.z, a);
              a = fmaf(zS[(d+3)*128 + tl], cv.w, a);
            }
            accs[ci] = a;
          }
        }
        if (ovf){
          const float* cr = cb + (size_t)eIdx * Dd + ch*64;
          float a = accE;
          #pragma unroll
          for (int d = 0; d < 64; d += 4){
            const float4 cv = *(const float4*)(cr + d);
            a = fmaf(zS[(d+0)*128 + tl], cv.x, a);
            a = fmaf(zS[(d+1)*128 + tl], cv.y, a);
            a = fmaf(zS[(d+2)*128 + tl], cv.z, a);
            a = fmaf(zS[(d+3)*128 + tl], cv.w, a);
          }
          accE = a;
        }
      }
    }

    if (act){
      float bv = 3.4e38f; int bi = 0x7fffffff;
      #pragma unroll
      for (int ci = 0; ci < CCAP; ci++){
        if (ci < n){
          const int ix = (int)cds[ci];
          float t  = za - 2.0f * accs[ci];
          float d2 = t + cnS[ix];
          if (d2 < bv || (d2 == bv && ix < bi)){ bv = d2; bi = ix; }
        }
      }
      if (ovf){
        float t  = za - 2.0f * accE;
        float d2 = t + cnS[eIdx];
        if (d2 < bv || (d2 == bv && eIdx < bi)){ bv = d2; bi = eIdx; }
      }
      idsW[tok] = bi;
      out[(size_t)2 * Nn * Dd + tok] = (float)bi;
    }
  }
}

// ---------- phase 2: d-plane output streamer ----------
__global__ __launch_bounds__(256) void vq_out_k(const float* __restrict__ cbT,
                                                const int* __restrict__ idsW,
                                                float* __restrict__ out){
  __shared__ float rows[8*1024];     // 32 KiB
  __shared__ int   idsS[2048];       // 8 KiB
  const int tid = threadIdx.x, blk = blockIdx.x;
  const int b = blk >> 8, dg = (blk >> 3) & 31, sc = blk & 7;

  const float4* src = (const float4*)(cbT + (size_t)dg*8*1024);
  #pragma unroll
  for (int r = 0; r < 8; r++)
    ((float4*)rows)[r*256 + tid] = src[r*256 + tid];
  const int4* ip = (const int4*)(idsW + (size_t)b*SPB + sc*2048);
  ((int4*)idsS)[tid]       = ip[tid];
  ((int4*)idsS)[256 + tid] = ip[256 + tid];
  __syncthreads();

  #pragma unroll
  for (int d = 0; d < 8; d++){
    float* q  = out + (size_t)(b*256 + dg*8 + d) * SPB + sc*2048;
    float* st = q + (size_t)Nn * Dd;
    const float* rd = rows + d*1024;
    #pragma unroll
    for (int k = 0; k < 2; k++){
      const int p = k*256 + tid;
      const int4 iv = ((const int4*)idsS)[p];
      float4 v;
      v.x = rd[iv.x]; v.y = rd[iv.y]; v.z = rd[iv.z]; v.w = rd[iv.w];
      ((float4*)q)[p]  = v;
      ((float4*)st)[p] = v;
    }
  }
}

// ================= R1 fp32 fallback (used if ws too small) =================
#define MICRO_STEP(WITH_ZN)                                                    \
    {                                                                          \
        float4 a0 = *(const float4*)&As[d][ty * 8];                            \
        float4 a1 = *(const float4*)&As[d][ty * 8 + 4];                        \
        float4 b0 = *(const float4*)&Bs[d][tx * 8];                            \
        float4 b1 = *(const float4*)&Bs[d][tx * 8 + 4];                        \
        float a[8] = {a0.x, a0.y, a0.z, a0.w, a1.x, a1.y, a1.z, a1.w};         \
        float bb[8] = {b0.x, b0.y, b0.z, b0.w, b1.x, b1.y, b1.z, b1.w};        \
        _Pragma("unroll")                                                      \
        for (int i = 0; i < 8; i++) {                                          \
            _Pragma("unroll")                                                  \
            for (int j = 0; j < 8; j++) acc[i][j] += a[i] * bb[j];             \
            if (WITH_ZN) zn[i] += a[i] * a[i];                                 \
        }                                                                      \
    }

__global__ __launch_bounds__(256) void vq_k(const float* __restrict__ z,
                                            const float* __restrict__ cb,
                                            const float* __restrict__ cn,
                                            float* __restrict__ out){
  __shared__ float As[16][128];
  __shared__ float Bs[16][132];
  __shared__ int   idsf[128];
  const int tid = threadIdx.x;
  const int tx = tid & 15, ty = tid >> 4;
  const int blk = blockIdx.x;
  const int b = blk >> 7, sb = (blk & 127) * 128;
  const float* zb = z + (size_t)b * Dd * SPB + sb;
  float bestv[8]; int besti[8]; float zn[8];
  #pragma unroll
  for (int i = 0; i < 8; i++){ bestv[i] = 3.4e38f; besti[i] = 0; zn[i] = 0.f; }
  const int am = tid & 127, ad = tid >> 7;
  const int bd = tid & 15,  bk = tid >> 4;
  for (int cc = 0; cc < 8; cc++){
    float acc[8][8];
    #pragma unroll
    for (int i = 0; i < 8; i++)
      #pragma unroll
      for (int j = 0; j < 8; j++) acc[i][j] = 0.f;
    for (int dc = 0; dc < 16; dc++){
      #pragma unroll
      for (int r = 0; r < 8; r++){
        const int d = ad + r * 2;
        As[d][am] = zb[(size_t)(dc*16 + d) * SPB + am];
      }
      #pragma unroll
      for (int r = 0; r < 8; r++){
        const int k = bk + r * 16;
        Bs[bd][k] = cb[(size_t)(cc*128 + k) * Dd + dc*16 + bd];
      }
      __syncthreads();
      if (cc == 0){
        #pragma unroll
        for (int d = 0; d < 16; d++) MICRO_STEP(1)
      } else {
        #pragma unroll
        for (int d = 0; d < 16; d++) MICRO_STEP(0)
      }
      __syncthreads();
    }
    const float* cnp = cn + cc*128 + tx*8;
    float4 c0 = *(const float4*)cnp;
    float4 c1 = *(const float4*)(cnp + 4);
    float cv[8] = {c0.x, c0.y, c0.z, c0.w, c1.x, c1.y, c1.z, c1.w};
    #pragma unroll
    for (int i = 0; i < 8; i++){
      #pragma unroll
      for (int j = 0; j < 8; j++){
        float t  = zn[i] - 2.0f * acc[i][j];
        float d2 = t + cv[j];
        int   ix = cc*128 + tx*8 + j;
        if (d2 < bestv[i]){ bestv[i] = d2; besti[i] = ix; }
      }
    }
  }
  #pragma unroll
  for (int i = 0; i < 8; i++){
    float v = bestv[i]; int ix = besti[i];
    #pragma unroll
    for (int off = 8; off > 0; off >>= 1){
      float ov = __shfl_down(v, off, 16);
      int   oi = __shfl_down(ix, off, 16);
      if (ov < v || (ov == v && oi < ix)){ v = ov; ix = oi; }
    }
    if (tx == 0) idsf[ty*8 + i] = ix;
  }
  __syncthreads();
  if (tid < 128) out[(size_t)2*Nn*Dd + (size_t)blk*128 + tid] = (float)idsf[tid];
  const int m = tid & 127, cg = tid >> 7;
  const int myidx = idsf[m];
  const float* crow = cb + (size_t)myidx * Dd + cg*128;
  float* q  = out + (size_t)b * Dd * SPB + (size_t)cg * 128 * SPB + sb + m;
  float* st = q + (size_t)Nn * Dd;
  #pragma unroll 8
  for (int r = 0; r < 128; r++){
    const float v = crow[r];
    q[(size_t)r * SPB]  = v;
    st[(size_t)r * SPB] = v;
  }
}

// ---------- launcher ----------
extern "C" void kernel_launch(void* const* d_in, const int* in_sizes, int n_in,
                              void* d_out, int out_size, void* d_ws, size_t ws_size,
                              hipStream_t stream){
  const float* z  = (const float*)d_in[0];
  const float* cb = (const float*)d_in[1];
  float* out = (float*)d_out;

  const size_t BG_B  = (size_t)4 * 8 * 1024 * 16;     // 512 KiB
  const size_t CN_B  = (size_t)Kk * 4;                // 4 KiB
  const size_t CBT_B = (size_t)Dd * Kk * 4;           // 1 MiB
  const size_t IDS_B = (size_t)Nn * 4;                // 512 KiB
  const size_t NEED = BG_B + CN_B + CBT_B + IDS_B;

  if (ws_size >= NEED){
    uint8_t* ws = (uint8_t*)d_ws;
    size_t o = 0;
    uint4* Bg   = (uint4*)(ws + o);          o += BG_B;
    float* cnG  = (float*)(ws + o);          o += CN_B;
    float* cbT  = (float*)(ws + o);          o += CBT_B;
    int*   idsW = (int*)(ws + o);            o += IDS_B;

    cnorm_k<<<Kk, 64, 0, stream>>>(cb, cnG);
    cconv_k<<<4, 256, 0, stream>>>(cb, Bg, cbT);
    vq_sweep_k<<<Nn/128, 512, 0, stream>>>(z, cb, Bg, cnG, idsW, out);
    vq_out_k<<<Nn/64, 256, 0, stream>>>(cbT, idsW, out);
  } else {
    float* cn = (float*)d_ws;
    cnorm_k<<<Kk, 64, 0, stream>>>(cb, cn);
    vq_k<<<Nn/128, 256, 0, stream>>>(z, cb, cn, out);
  }
}